// Round 3
// baseline (278.488 us; speedup 1.0000x reference)
//
#include <hip/hip_runtime.h>
#include <hip/hip_bf16.h>
#include <cmath>

#define D_MODEL 1024
#define N_HEADS 16
#define HEAD_DIM 64
#define SEQ 2048
#define BATCH 2
#define MROWS (BATCH * SEQ)  // 4096

typedef __bf16 bf16;
typedef __bf16 bf16x8 __attribute__((ext_vector_type(8)));
typedef __bf16 bf16x4 __attribute__((ext_vector_type(4)));
typedef float f32x4 __attribute__((ext_vector_type(4)));

// LDS swizzles: spread rows across 16B slots so wave-strided b128 reads are <=2-way.
#define SWZG(row, cbyte) ((row) * 64 + ((cbyte) ^ ((((row) >> 1) & 3) << 4)))    // 64B row stride
#define SWZA(row, cbyte) ((row) * 128 + ((cbyte) ^ (((row) & 7) << 4)))          // 128B row stride

// ---------------- fp32 -> bf16 convert (x) ----------------
__global__ __launch_bounds__(256) void cvt_x(const float* __restrict__ x,
                                             bf16* __restrict__ xb) {
    int i = blockIdx.x * 256 + threadIdx.x;
    float4 v = ((const float4*)x)[i];
    bf16x4 o = { (bf16)v.x, (bf16)v.y, (bf16)v.z, (bf16)v.w };
    ((bf16x4*)xb)[i] = o;
}

// ---------------- weight transpose + convert: wt[z][n][k] = W_z[k][n] ----------------
__global__ void cvt_wt(const float* __restrict__ Wq, const float* __restrict__ Wk,
                       const float* __restrict__ Wv, const float* __restrict__ Wo,
                       bf16* __restrict__ wt) {
    __shared__ float tile[32][33];
    int z = blockIdx.z;
    const float* W = (z == 0) ? Wq : (z == 1) ? Wk : (z == 2) ? Wv : Wo;
    int n0 = blockIdx.x * 32, k0 = blockIdx.y * 32;
    int tx = threadIdx.x, ty = threadIdx.y;
    tile[ty][tx] = W[(size_t)(k0 + ty) * D_MODEL + n0 + tx];
    __syncthreads();
    wt[(size_t)z * D_MODEL * D_MODEL + (size_t)(n0 + ty) * D_MODEL + k0 + tx] =
        (bf16)tile[tx][ty];
}

// ---------------- GEMM: Y[M,N] = A[M,K] @ Wt[N,K]^T + bias ----------------
// MODE 0: write bf16 scattered to [B*H, S, Hd] (QKV).  MODE 1: write f32 [M, N] (out proj).
template <int MODE>
__global__ __launch_bounds__(256) void gemm_k(const bf16* __restrict__ A,
                                              const bf16* __restrict__ Bt,
                                              const float* __restrict__ bias,
                                              void* __restrict__ outp) {
    constexpr int BM = 128, BK = 32, KDIM = D_MODEL;
    __shared__ alignas(16) bf16 As[BM * BK];
    __shared__ alignas(16) bf16 Bs[BM * BK];
    char* Asb = (char*)As;
    char* Bsb = (char*)Bs;
    const int tid = threadIdx.x;
    const int wid = tid >> 6, lane = tid & 63;
    const int m0 = blockIdx.y * BM, n0 = blockIdx.x * BM;
    const int wr = (wid >> 1) * 64, wc = (wid & 1) * 64;
    f32x4 acc[4][4] = {};

    for (int k0 = 0; k0 < KDIM; k0 += BK) {
        __syncthreads();
#pragma unroll
        for (int c = 0; c < 2; ++c) {
            int idx = tid + c * 256;
            int row = idx >> 2, cb = (idx & 3) * 16;  // byte col within 64B row
            *(bf16x8*)(Asb + SWZG(row, cb)) =
                *(const bf16x8*)&A[(size_t)(m0 + row) * KDIM + k0 + (cb >> 1)];
            *(bf16x8*)(Bsb + SWZG(row, cb)) =
                *(const bf16x8*)&Bt[(size_t)(n0 + row) * KDIM + k0 + (cb >> 1)];
        }
        __syncthreads();
        const int cb = (lane >> 4) * 16;
        bf16x8 a[4], b[4];
#pragma unroll
        for (int m = 0; m < 4; ++m) {
            int r = wr + m * 16 + (lane & 15);
            a[m] = *(bf16x8*)(Asb + SWZG(r, cb));
        }
#pragma unroll
        for (int n = 0; n < 4; ++n) {
            int r = wc + n * 16 + (lane & 15);
            b[n] = *(bf16x8*)(Bsb + SWZG(r, cb));
        }
#pragma unroll
        for (int m = 0; m < 4; ++m)
#pragma unroll
            for (int n = 0; n < 4; ++n)
                acc[m][n] = __builtin_amdgcn_mfma_f32_16x16x32_bf16(a[m], b[n], acc[m][n], 0, 0, 0);
    }

#pragma unroll
    for (int m = 0; m < 4; ++m)
#pragma unroll
        for (int n = 0; n < 4; ++n)
#pragma unroll
            for (int r = 0; r < 4; ++r) {
                int grow = m0 + wr + m * 16 + (lane >> 4) * 4 + r;
                int gcol = n0 + wc + n * 16 + (lane & 15);
                float val = acc[m][n][r] + bias[gcol];
                if (MODE == 0) {
                    int b_ = grow >> 11, s_ = grow & 2047;
                    int h = gcol >> 6, hd = gcol & 63;
                    ((bf16*)outp)[((size_t)(b_ * N_HEADS + h) * SEQ + s_) * HEAD_DIM + hd] =
                        (bf16)val;
                } else {
                    ((float*)outp)[(size_t)grow * D_MODEL + gcol] = val;
                }
            }
}

// ---------------- flash-style causal attention ----------------
// grid (S/64, B*H), block 256. Q/K/V: [B*H, S, Hd] bf16. AO: [B*S, D] bf16.
__global__ __launch_bounds__(256) void attn_k(const bf16* __restrict__ Qg,
                                              const bf16* __restrict__ Kg,
                                              const bf16* __restrict__ Vg,
                                              bf16* __restrict__ AO) {
    __shared__ alignas(16) bf16 Ks[64 * 64];
    __shared__ alignas(16) bf16 Vt[64 * 64];
    __shared__ alignas(16) bf16 Ps[64 * 64];
    char* Ksb = (char*)Ks;
    char* Vtb = (char*)Vt;
    char* Psb = (char*)Ps;
    const int tid = threadIdx.x, wid = tid >> 6, lane = tid & 63;
    const int q0 = blockIdx.x * 64;
    const int bh = blockIdx.y;
    const size_t base = (size_t)bh * SEQ * HEAD_DIM;

    bf16x8 aq[2];
    {
        int qr = q0 + wid * 16 + (lane & 15);
        const bf16* qrow = &Qg[base + (size_t)qr * HEAD_DIM];
        aq[0] = *(const bf16x8*)&qrow[(lane >> 4) * 8];
        aq[1] = *(const bf16x8*)&qrow[32 + (lane >> 4) * 8];
    }
    f32x4 o[4] = {};
    float mrow[4], lrow[4];
#pragma unroll
    for (int r = 0; r < 4; ++r) { mrow[r] = -__builtin_inff(); lrow[r] = 0.f; }

    for (int t0 = 0; t0 <= q0; t0 += 64) {
        __syncthreads();
#pragma unroll
        for (int c = 0; c < 2; ++c) {
            int idx = tid + c * 256;
            int row = idx >> 3, col8 = (idx & 7) * 8;
            *(bf16x8*)(Ksb + SWZA(row, col8 * 2)) =
                *(const bf16x8*)&Kg[base + (size_t)(t0 + row) * HEAD_DIM + col8];
            bf16x8 vv = *(const bf16x8*)&Vg[base + (size_t)(t0 + row) * HEAD_DIM + col8];
#pragma unroll
            for (int j = 0; j < 8; ++j) {
                int d = col8 + j;
                *(bf16*)(Vtb + d * 128 + ((2 * row) ^ ((d & 7) << 4))) = vv[j];
            }
        }
        __syncthreads();

        const int cb = (lane >> 4) * 16;
        f32x4 s[4];
#pragma unroll
        for (int tf = 0; tf < 4; ++tf) {
            int tr = tf * 16 + (lane & 15);
            bf16x8 b0 = *(bf16x8*)(Ksb + SWZA(tr, cb));
            bf16x8 b1 = *(bf16x8*)(Ksb + SWZA(tr, 64 + cb));
            f32x4 z = {};
            z = __builtin_amdgcn_mfma_f32_16x16x32_bf16(aq[0], b0, z, 0, 0, 0);
            z = __builtin_amdgcn_mfma_f32_16x16x32_bf16(aq[1], b1, z, 0, 0, 0);
            s[tf] = z;
        }
#pragma unroll
        for (int tf = 0; tf < 4; ++tf)
#pragma unroll
            for (int r = 0; r < 4; ++r) {
                int gq = q0 + wid * 16 + (lane >> 4) * 4 + r;
                int gt = t0 + tf * 16 + (lane & 15);
                float v = s[tf][r] * 0.125f;
                s[tf][r] = (gt <= gq) ? v : -__builtin_inff();
            }
        float mx[4];
#pragma unroll
        for (int r = 0; r < 4; ++r)
            mx[r] = fmaxf(fmaxf(s[0][r], s[1][r]), fmaxf(s[2][r], s[3][r]));
#pragma unroll
        for (int off = 1; off < 16; off <<= 1)
#pragma unroll
            for (int r = 0; r < 4; ++r) mx[r] = fmaxf(mx[r], __shfl_xor(mx[r], off));
        float sf[4];
#pragma unroll
        for (int r = 0; r < 4; ++r) {
            float mn = fmaxf(mrow[r], mx[r]);
            sf[r] = __expf(mrow[r] - mn);
            mrow[r] = mn;
        }
        float rs[4] = {0.f, 0.f, 0.f, 0.f};
#pragma unroll
        for (int tf = 0; tf < 4; ++tf)
#pragma unroll
            for (int r = 0; r < 4; ++r) {
                float p = __expf(s[tf][r] - mrow[r]);
                s[tf][r] = p;
                rs[r] += p;
            }
#pragma unroll
        for (int off = 1; off < 16; off <<= 1)
#pragma unroll
            for (int r = 0; r < 4; ++r) rs[r] += __shfl_xor(rs[r], off);
#pragma unroll
        for (int r = 0; r < 4; ++r) lrow[r] = lrow[r] * sf[r] + rs[r];
#pragma unroll
        for (int nf = 0; nf < 4; ++nf)
#pragma unroll
            for (int r = 0; r < 4; ++r) o[nf][r] *= sf[r];
#pragma unroll
        for (int tf = 0; tf < 4; ++tf)
#pragma unroll
            for (int r = 0; r < 4; ++r) {
                int i = wid * 16 + (lane >> 4) * 4 + r;
                int t = tf * 16 + (lane & 15);
                *(bf16*)(Psb + i * 128 + ((2 * t) ^ ((i & 7) << 4))) = (bf16)s[tf][r];
            }
        __syncthreads();  // order P write -> P read (cheap, also keeps waves together)
#pragma unroll
        for (int kc = 0; kc < 2; ++kc) {
            int i = wid * 16 + (lane & 15);
            bf16x8 ap = *(bf16x8*)(Psb + SWZA(i, kc * 64 + cb));
#pragma unroll
            for (int nf = 0; nf < 4; ++nf) {
                int d = nf * 16 + (lane & 15);
                bf16x8 bv = *(bf16x8*)(Vtb + SWZA(d, kc * 64 + cb));
                o[nf] = __builtin_amdgcn_mfma_f32_16x16x32_bf16(ap, bv, o[nf], 0, 0, 0);
            }
        }
    }

    int b_ = bh >> 4, h = bh & 15;
#pragma unroll
    for (int nf = 0; nf < 4; ++nf)
#pragma unroll
        for (int r = 0; r < 4; ++r) {
            int i = wid * 16 + (lane >> 4) * 4 + r;
            int s_ = q0 + i;
            float val = o[nf][r] / lrow[r];
            AO[((size_t)(b_ * SEQ + s_)) * D_MODEL + h * HEAD_DIM + nf * 16 + (lane & 15)] =
                (bf16)val;
        }
}

extern "C" void kernel_launch(void* const* d_in, const int* in_sizes, int n_in,
                              void* d_out, int out_size, void* d_ws, size_t ws_size,
                              hipStream_t stream) {
    const float* x  = (const float*)d_in[0];
    const float* Wq = (const float*)d_in[1];
    const float* bq = (const float*)d_in[2];
    const float* Wk = (const float*)d_in[3];
    const float* bk = (const float*)d_in[4];
    const float* Wv = (const float*)d_in[5];
    const float* bv = (const float*)d_in[6];
    const float* Wo = (const float*)d_in[7];
    const float* bo = (const float*)d_in[8];

    char* ws = (char*)d_ws;
    const size_t MB = 1u << 20;
    bf16* wt = (bf16*)ws;                  // 4 x [1024][1024] bf16 = 8 MB
    bf16* xb = (bf16*)(ws + 8 * MB);       // [4096][1024] bf16   = 8 MB
    bf16* Qb = (bf16*)(ws + 16 * MB);      // [32][2048][64] bf16 = 8 MB
    bf16* Kb = (bf16*)(ws + 24 * MB);
    bf16* Vb = (bf16*)(ws + 32 * MB);
    bf16* AO = (bf16*)(ws + 40 * MB);      // [4096][1024] bf16   = 8 MB

    const size_t WSTRIDE = (size_t)D_MODEL * D_MODEL;

    cvt_x<<<dim3(MROWS * D_MODEL / 4 / 256), dim3(256), 0, stream>>>(x, xb);
    cvt_wt<<<dim3(32, 32, 4), dim3(32, 32), 0, stream>>>(Wq, Wk, Wv, Wo, wt);

    gemm_k<0><<<dim3(8, 32), dim3(256), 0, stream>>>(xb, wt + 0 * WSTRIDE, bq, Qb);
    gemm_k<0><<<dim3(8, 32), dim3(256), 0, stream>>>(xb, wt + 1 * WSTRIDE, bk, Kb);
    gemm_k<0><<<dim3(8, 32), dim3(256), 0, stream>>>(xb, wt + 2 * WSTRIDE, bv, Vb);

    attn_k<<<dim3(SEQ / 64, BATCH * N_HEADS), dim3(256), 0, stream>>>(Qb, Kb, Vb, AO);

    gemm_k<1><<<dim3(8, 32), dim3(256), 0, stream>>>(AO, wt + 3 * WSTRIDE, bo, d_out);
}

// Round 5
// 202.614 us; speedup vs baseline: 1.3745x; 1.3745x over previous
//
#include <hip/hip_runtime.h>
#include <hip/hip_bf16.h>
#include <cmath>

#define D_MODEL 1024
#define N_HEADS 16
#define HEAD_DIM 64
#define SEQ 2048
#define BATCH 2
#define MROWS (BATCH * SEQ)  // 4096

typedef __bf16 bf16;
typedef __bf16 bf16x8 __attribute__((ext_vector_type(8)));
typedef __bf16 bf16x4 __attribute__((ext_vector_type(4)));
typedef float f32x4 __attribute__((ext_vector_type(4)));

// K-tile swizzle (128B rows): byte = row*128 + (cbyte ^ ((row&7)<<4)).
#define SWZA(row, cbyte) ((row) * 128 + ((cbyte) ^ (((row) & 7) << 4)))
// GEMM LDS swizzle (64B rows)
#define SWZG(row, cbyte) ((row) * 64 + ((cbyte) ^ ((((row) >> 1) & 3) << 4)))
// Vt swizzle: element (d,t) at byte d*128 + 2*(t ^ SVD(d)). Write: 2 lanes/bank (free).
// Read (b128, t0 8-aligned): 8 balanced 4-bank groups (optimal).
#define SVD(d) (((((d) >> 3) & 1) << 5) | ((((d) >> 4) & 3) << 3))

// ---------------- fp32 -> bf16 convert (x) ----------------
__global__ __launch_bounds__(256) void cvt_x(const float* __restrict__ x,
                                             bf16* __restrict__ xb) {
    int i = blockIdx.x * 256 + threadIdx.x;
    float4 v = ((const float4*)x)[i];
    bf16x4 o = { (bf16)v.x, (bf16)v.y, (bf16)v.z, (bf16)v.w };
    ((bf16x4*)xb)[i] = o;
}

// ---------------- weight transpose + convert: wt[z][n][k] = W_z[k][n] ----------------
__global__ void cvt_wt(const float* __restrict__ Wq, const float* __restrict__ Wk,
                       const float* __restrict__ Wv, const float* __restrict__ Wo,
                       bf16* __restrict__ wt) {
    __shared__ float tile[32][33];
    int z = blockIdx.z;
    const float* W = (z == 0) ? Wq : (z == 1) ? Wk : (z == 2) ? Wv : Wo;
    int n0 = blockIdx.x * 32, k0 = blockIdx.y * 32;
    int tx = threadIdx.x, ty = threadIdx.y;
    tile[ty][tx] = W[(size_t)(k0 + ty) * D_MODEL + n0 + tx];
    __syncthreads();
    wt[(size_t)z * D_MODEL * D_MODEL + (size_t)(n0 + ty) * D_MODEL + k0 + tx] =
        (bf16)tile[tx][ty];
}

// ---------------- GEMM: Y[M,N] = A[M,K] @ Wt[N,K]^T + bias ----------------
// MODE 0: fused QKV, N = 3072 (z = gcol>>10 selects Q/K/V), bf16 out scattered
//         to [z][B*H, S, Hd] (consecutive 4Mi-elem buffers).
// MODE 1: out proj, N = 1024, f32 out [M, N].
template <int MODE>
__global__ __launch_bounds__(256) void gemm_k(const bf16* __restrict__ A,
                                              const bf16* __restrict__ Bt,
                                              const float* __restrict__ b0,
                                              const float* __restrict__ b1,
                                              const float* __restrict__ b2,
                                              void* __restrict__ outp) {
    constexpr int BM = 128, BK = 32, KDIM = D_MODEL;
    __shared__ alignas(16) bf16 As[BM * BK];
    __shared__ alignas(16) bf16 Bs[BM * BK];
    char* Asb = (char*)As;
    char* Bsb = (char*)Bs;
    const int tid = threadIdx.x;
    const int wid = tid >> 6, lane = tid & 63;
    const int m0 = blockIdx.y * BM, n0 = blockIdx.x * BM;
    const int wr = (wid >> 1) * 64, wc = (wid & 1) * 64;
    f32x4 acc[4][4] = {};

    for (int k0 = 0; k0 < KDIM; k0 += BK) {
        __syncthreads();
#pragma unroll
        for (int c = 0; c < 2; ++c) {
            int idx = tid + c * 256;
            int row = idx >> 2, cb = (idx & 3) * 16;
            *(bf16x8*)(Asb + SWZG(row, cb)) =
                *(const bf16x8*)&A[(size_t)(m0 + row) * KDIM + k0 + (cb >> 1)];
            *(bf16x8*)(Bsb + SWZG(row, cb)) =
                *(const bf16x8*)&Bt[(size_t)(n0 + row) * KDIM + k0 + (cb >> 1)];
        }
        __syncthreads();
        const int cb = (lane >> 4) * 16;
        bf16x8 a[4], b[4];
#pragma unroll
        for (int m = 0; m < 4; ++m) {
            int r = wr + m * 16 + (lane & 15);
            a[m] = *(bf16x8*)(Asb + SWZG(r, cb));
        }
#pragma unroll
        for (int n = 0; n < 4; ++n) {
            int r = wc + n * 16 + (lane & 15);
            b[n] = *(bf16x8*)(Bsb + SWZG(r, cb));
        }
#pragma unroll
        for (int m = 0; m < 4; ++m)
#pragma unroll
            for (int n = 0; n < 4; ++n)
                acc[m][n] = __builtin_amdgcn_mfma_f32_16x16x32_bf16(a[m], b[n], acc[m][n], 0, 0, 0);
    }

    const int z = n0 >> 10;  // block-uniform (128 | 1024)
    const float* bias = (MODE == 1) ? b0 : ((z == 0) ? b0 : (z == 1) ? b1 : b2);
#pragma unroll
    for (int m = 0; m < 4; ++m)
#pragma unroll
        for (int n = 0; n < 4; ++n)
#pragma unroll
            for (int r = 0; r < 4; ++r) {
                int grow = m0 + wr + m * 16 + (lane >> 4) * 4 + r;
                int gcol = n0 + wc + n * 16 + (lane & 15);
                if (MODE == 0) {
                    int colN = gcol & 1023;
                    float val = acc[m][n][r] + bias[colN];
                    int b_ = grow >> 11, s_ = grow & 2047;
                    int h = colN >> 6, hd = colN & 63;
                    ((bf16*)outp)[(size_t)z * 4194304 +
                                  ((size_t)(b_ * N_HEADS + h) * SEQ + s_) * HEAD_DIM + hd] =
                        (bf16)val;
                } else {
                    float val = acc[m][n][r] + bias[gcol];
                    ((float*)outp)[(size_t)grow * D_MODEL + gcol] = val;
                }
            }
}

// ---------------- flash-style causal attention ----------------
// grid (S/64, B*H), block 256 (4 waves x 16 q-rows). Q/K/V: [B*H, S, Hd] bf16.
// Double-buffered K/Vt LDS, async reg-staging (T14), 1 barrier/tile,
// wave-private Ps (no barrier), conflict-free swizzles throughout.
__global__ __launch_bounds__(256) void attn_k(const bf16* __restrict__ Qg,
                                              const bf16* __restrict__ Kg,
                                              const bf16* __restrict__ Vg,
                                              bf16* __restrict__ AO) {
    __shared__ alignas(16) bf16 Ks[2][64 * 64];
    __shared__ alignas(16) bf16 Vt[2][64 * 64];
    __shared__ alignas(16) bf16 Ps[64 * 64];
    char* Psb = (char*)Ps;
    const int tid = threadIdx.x, wid = tid >> 6, lane = tid & 63;
    const int m = lane & 15, h = lane >> 4;
    // reversed launch order: heavy (large q0) blocks first
    const int q0 = ((int)gridDim.x - 1 - (int)blockIdx.x) * 64;
    const int bh = blockIdx.y;
    const size_t base = (size_t)bh * SEQ * HEAD_DIM;

    // Q fragments: lane holds Q[q0 + wid*16 + m][kc*32 + h*8 + j]
    bf16x8 aq[2];
    {
        const bf16* qrow = &Qg[base + (size_t)(q0 + wid * 16 + m) * HEAD_DIM];
        aq[0] = *(const bf16x8*)&qrow[h * 8];
        aq[1] = *(const bf16x8*)&qrow[32 + h * 8];
    }

    // staging geometry: thread covers rows r0 and r0+32, 8 d's at c8
    const int r0 = tid >> 3, c8 = (tid & 7) * 8;
    bf16x8 kreg[2], vreg[2];

    f32x4 o[4] = {};
    float mrow[4], lrow[4];
#pragma unroll
    for (int r = 0; r < 4; ++r) { mrow[r] = -__builtin_inff(); lrow[r] = 0.f; }

    const int nt = (q0 >> 6) + 1;

    // prologue: stage tile 0 into buf 0
    {
        const bf16* kp = &Kg[base + (size_t)r0 * HEAD_DIM + c8];
        const bf16* vp = &Vg[base + (size_t)r0 * HEAD_DIM + c8];
        kreg[0] = *(const bf16x8*)kp;
        vreg[0] = *(const bf16x8*)vp;
        kreg[1] = *(const bf16x8*)(kp + 32 * HEAD_DIM);
        vreg[1] = *(const bf16x8*)(vp + 32 * HEAD_DIM);
#pragma unroll
        for (int c = 0; c < 2; ++c) {
            int row = r0 + c * 32;
            *(bf16x8*)((char*)&Ks[0][0] + SWZA(row, c8 * 2)) = kreg[c];
#pragma unroll
            for (int j = 0; j < 8; ++j) {
                int d = c8 + j;
                *(bf16*)((char*)&Vt[0][0] + d * 128 + 2 * (row ^ SVD(d))) = vreg[c][j];
            }
        }
    }

    for (int it = 0; it < nt; ++it) {
        __syncthreads();  // buf[cur] staged & visible; all waves past previous tile
        const int t0 = it * 64, cur = it & 1;

        // async: issue next tile's global loads now (consumed at end of iter)
        if (it + 1 < nt) {
            const bf16* kp = &Kg[base + (size_t)(t0 + 64 + r0) * HEAD_DIM + c8];
            const bf16* vp = &Vg[base + (size_t)(t0 + 64 + r0) * HEAD_DIM + c8];
            kreg[0] = *(const bf16x8*)kp;
            vreg[0] = *(const bf16x8*)vp;
            kreg[1] = *(const bf16x8*)(kp + 32 * HEAD_DIM);
            vreg[1] = *(const bf16x8*)(vp + 32 * HEAD_DIM);
        }

        // ---- QK^T ----
        char* Kb = (char*)&Ks[cur][0];
        const int cb = h * 16;
        f32x4 s[4];
        __builtin_amdgcn_s_setprio(1);
#pragma unroll
        for (int tf = 0; tf < 4; ++tf) {
            int tr = tf * 16 + m;
            bf16x8 b0v = *(bf16x8*)(Kb + SWZA(tr, cb));
            bf16x8 b1v = *(bf16x8*)(Kb + SWZA(tr, 64 + cb));
            f32x4 z = {};
            z = __builtin_amdgcn_mfma_f32_16x16x32_bf16(aq[0], b0v, z, 0, 0, 0);
            z = __builtin_amdgcn_mfma_f32_16x16x32_bf16(aq[1], b1v, z, 0, 0, 0);
            s[tf] = z;
        }
        __builtin_amdgcn_s_setprio(0);

        // scale; mask only on the diagonal tile
#pragma unroll
        for (int tf = 0; tf < 4; ++tf)
#pragma unroll
            for (int r = 0; r < 4; ++r) s[tf][r] *= 0.125f;
        if (t0 == q0) {
#pragma unroll
            for (int tf = 0; tf < 4; ++tf)
#pragma unroll
                for (int r = 0; r < 4; ++r) {
                    int gq = wid * 16 + h * 4 + r;
                    int gt = tf * 16 + m;
                    if (gt > gq) s[tf][r] = -__builtin_inff();
                }
        }

        // ---- online softmax (rows split across 16-lane groups) ----
        float mx[4];
#pragma unroll
        for (int r = 0; r < 4; ++r)
            mx[r] = fmaxf(fmaxf(s[0][r], s[1][r]), fmaxf(s[2][r], s[3][r]));
#pragma unroll
        for (int off = 1; off < 16; off <<= 1)
#pragma unroll
            for (int r = 0; r < 4; ++r) mx[r] = fmaxf(mx[r], __shfl_xor(mx[r], off));
        float sf[4];
#pragma unroll
        for (int r = 0; r < 4; ++r) {
            float mn = fmaxf(mrow[r], mx[r]);
            sf[r] = __expf(mrow[r] - mn);
            mrow[r] = mn;
        }
        float rs[4] = {0.f, 0.f, 0.f, 0.f};
#pragma unroll
        for (int tf = 0; tf < 4; ++tf)
#pragma unroll
            for (int r = 0; r < 4; ++r) {
                float p = __expf(s[tf][r] - mrow[r]);
                s[tf][r] = p;
                rs[r] += p;
            }
#pragma unroll
        for (int off = 1; off < 16; off <<= 1)
#pragma unroll
            for (int r = 0; r < 4; ++r) rs[r] += __shfl_xor(rs[r], off);
#pragma unroll
        for (int r = 0; r < 4; ++r) lrow[r] = lrow[r] * sf[r] + rs[r];
#pragma unroll
        for (int nf = 0; nf < 4; ++nf)
#pragma unroll
            for (int r = 0; r < 4; ++r) o[nf][r] *= sf[r];

        // ---- P -> LDS (wave-private rows, no barrier) ----
#pragma unroll
        for (int tf = 0; tf < 4; ++tf)
#pragma unroll
            for (int r = 0; r < 4; ++r) {
                int i = wid * 16 + h * 4 + r;
                int t = tf * 16 + m;
                *(bf16*)(Psb + i * 128 + ((2 * t) ^ (h << 5))) = (bf16)s[tf][r];
            }

        // ---- PV ----
        char* Vb = (char*)&Vt[cur][0];
        __builtin_amdgcn_s_setprio(1);
#pragma unroll
        for (int kc = 0; kc < 2; ++kc) {
            int i_row = wid * 16 + m;
            bf16x8 ap = *(bf16x8*)(Psb + i_row * 128 +
                                   ((2 * (kc * 32 + h * 8)) ^ ((m >> 2) << 5)));
#pragma unroll
            for (int nf = 0; nf < 4; ++nf) {
                int d = nf * 16 + m;
                bf16x8 bv = *(bf16x8*)(Vb + d * 128 + 2 * ((kc * 32 + h * 8) ^ SVD(d)));
                o[nf] = __builtin_amdgcn_mfma_f32_16x16x32_bf16(ap, bv, o[nf], 0, 0, 0);
            }
        }
        __builtin_amdgcn_s_setprio(0);

        // ---- commit next tile to the other buffer (safe: all waves past its readers) ----
        if (it + 1 < nt) {
            const int nb = cur ^ 1;
#pragma unroll
            for (int c = 0; c < 2; ++c) {
                int row = r0 + c * 32;
                *(bf16x8*)((char*)&Ks[nb][0] + SWZA(row, c8 * 2)) = kreg[c];
#pragma unroll
                for (int j = 0; j < 8; ++j) {
                    int d = c8 + j;
                    *(bf16*)((char*)&Vt[nb][0] + d * 128 + 2 * (row ^ SVD(d))) = vreg[c][j];
                }
            }
        }
    }

    int b_ = bh >> 4, hh = bh & 15;
#pragma unroll
    for (int nf = 0; nf < 4; ++nf)
#pragma unroll
        for (int r = 0; r < 4; ++r) {
            int i = wid * 16 + h * 4 + r;
            int s_ = q0 + i;
            float val = o[nf][r] / lrow[r];
            AO[((size_t)(b_ * SEQ + s_)) * D_MODEL + hh * HEAD_DIM + nf * 16 + m] =
                (bf16)val;
        }
}

extern "C" void kernel_launch(void* const* d_in, const int* in_sizes, int n_in,
                              void* d_out, int out_size, void* d_ws, size_t ws_size,
                              hipStream_t stream) {
    const float* x  = (const float*)d_in[0];
    const float* Wq = (const float*)d_in[1];
    const float* bq = (const float*)d_in[2];
    const float* Wk = (const float*)d_in[3];
    const float* bk = (const float*)d_in[4];
    const float* Wv = (const float*)d_in[5];
    const float* bv = (const float*)d_in[6];
    const float* Wo = (const float*)d_in[7];
    const float* bo = (const float*)d_in[8];

    char* ws = (char*)d_ws;
    const size_t MB = 1u << 20;
    bf16* wt = (bf16*)ws;                  // 4 x [1024][1024] bf16 = 8 MB (QKV contiguous)
    bf16* xb = (bf16*)(ws + 8 * MB);       // [4096][1024] bf16
    bf16* Qb = (bf16*)(ws + 16 * MB);      // [32][2048][64] bf16; Kb, Vb follow contiguously
    bf16* Kb = (bf16*)(ws + 24 * MB);
    bf16* Vb = (bf16*)(ws + 32 * MB);
    bf16* AO = (bf16*)(ws + 40 * MB);      // [4096][1024] bf16

    const size_t WSTRIDE = (size_t)D_MODEL * D_MODEL;

    cvt_x<<<dim3(MROWS * D_MODEL / 4 / 256), dim3(256), 0, stream>>>(x, xb);
    cvt_wt<<<dim3(32, 32, 4), dim3(32, 32), 0, stream>>>(Wq, Wk, Wv, Wo, wt);

    // fused QKV projection: N = 3072 over contiguous [3072][1024] weight
    gemm_k<0><<<dim3(24, 32), dim3(256), 0, stream>>>(xb, wt, bq, bk, bv, Qb);

    attn_k<<<dim3(SEQ / 64, BATCH * N_HEADS), dim3(256), 0, stream>>>(Qb, Kb, Vb, AO);

    gemm_k<1><<<dim3(8, 32), dim3(256), 0, stream>>>(AO, wt + 3 * WSTRIDE, bo, bo, bo, d_out);
}

// Round 7
// 179.082 us; speedup vs baseline: 1.5551x; 1.1314x over previous
//
#include <hip/hip_runtime.h>
#include <hip/hip_bf16.h>
#include <cmath>

#define D_MODEL 1024
#define N_HEADS 16
#define HEAD_DIM 64
#define SEQ 2048
#define BATCH 2
#define MROWS (BATCH * SEQ)  // 4096

typedef __bf16 bf16;
typedef __bf16 bf16x8 __attribute__((ext_vector_type(8)));
typedef __bf16 bf16x4 __attribute__((ext_vector_type(4)));
typedef float f32x4 __attribute__((ext_vector_type(4)));

// GEMM LDS swizzle (64B rows)
#define SWZG(row, cbyte) ((row) * 64 + ((cbyte) ^ ((((row) >> 1) & 3) << 4)))

// ---------------- fp32 -> bf16 convert (x) ----------------
__global__ __launch_bounds__(256) void cvt_x(const float* __restrict__ x,
                                             bf16* __restrict__ xb) {
    int i = blockIdx.x * 256 + threadIdx.x;
    float4 v = ((const float4*)x)[i];
    bf16x4 o = { (bf16)v.x, (bf16)v.y, (bf16)v.z, (bf16)v.w };
    ((bf16x4*)xb)[i] = o;
}

// ---------------- weight transpose + convert: wt[z][n][k] = W_z[k][n] ----------------
__global__ void cvt_wt(const float* __restrict__ Wq, const float* __restrict__ Wk,
                       const float* __restrict__ Wv, const float* __restrict__ Wo,
                       bf16* __restrict__ wt) {
    __shared__ float tile[32][33];
    int z = blockIdx.z;
    const float* W = (z == 0) ? Wq : (z == 1) ? Wk : (z == 2) ? Wv : Wo;
    int n0 = blockIdx.x * 32, k0 = blockIdx.y * 32;
    int tx = threadIdx.x, ty = threadIdx.y;
    tile[ty][tx] = W[(size_t)(k0 + ty) * D_MODEL + n0 + tx];
    __syncthreads();
    wt[(size_t)z * D_MODEL * D_MODEL + (size_t)(n0 + ty) * D_MODEL + k0 + tx] =
        (bf16)tile[tx][ty];
}

// ---------------- GEMM: Y[M,N] = A[M,K] @ Wt[N,K]^T + bias ----------------
// MODE 0: fused QKV, N = 3072. z=0 -> Q[bh][t][d], z=1 -> K[bh][t][d],
//         z=2 -> V^T[bh][d][t]  (transposed here so attention loads B-frags direct).
// MODE 1: out proj, N = 1024, f32 out [M, N].
template <int MODE>
__global__ __launch_bounds__(256) void gemm_k(const bf16* __restrict__ A,
                                              const bf16* __restrict__ Bt,
                                              const float* __restrict__ b0,
                                              const float* __restrict__ b1,
                                              const float* __restrict__ b2,
                                              void* __restrict__ outp) {
    constexpr int BM = 128, BK = 32, KDIM = D_MODEL;
    __shared__ alignas(16) bf16 As[BM * BK];
    __shared__ alignas(16) bf16 Bs[BM * BK];
    char* Asb = (char*)As;
    char* Bsb = (char*)Bs;
    const int tid = threadIdx.x;
    const int wid = tid >> 6, lane = tid & 63;
    const int m0 = blockIdx.y * BM, n0 = blockIdx.x * BM;
    const int wr = (wid >> 1) * 64, wc = (wid & 1) * 64;
    f32x4 acc[4][4] = {};

    for (int k0 = 0; k0 < KDIM; k0 += BK) {
        __syncthreads();
#pragma unroll
        for (int c = 0; c < 2; ++c) {
            int idx = tid + c * 256;
            int row = idx >> 2, cb = (idx & 3) * 16;
            *(bf16x8*)(Asb + SWZG(row, cb)) =
                *(const bf16x8*)&A[(size_t)(m0 + row) * KDIM + k0 + (cb >> 1)];
            *(bf16x8*)(Bsb + SWZG(row, cb)) =
                *(const bf16x8*)&Bt[(size_t)(n0 + row) * KDIM + k0 + (cb >> 1)];
        }
        __syncthreads();
        const int cb = (lane >> 4) * 16;
        bf16x8 a[4], b[4];
#pragma unroll
        for (int m = 0; m < 4; ++m) {
            int r = wr + m * 16 + (lane & 15);
            a[m] = *(bf16x8*)(Asb + SWZG(r, cb));
        }
#pragma unroll
        for (int n = 0; n < 4; ++n) {
            int r = wc + n * 16 + (lane & 15);
            b[n] = *(bf16x8*)(Bsb + SWZG(r, cb));
        }
#pragma unroll
        for (int m = 0; m < 4; ++m)
#pragma unroll
            for (int n = 0; n < 4; ++n)
                acc[m][n] = __builtin_amdgcn_mfma_f32_16x16x32_bf16(a[m], b[n], acc[m][n], 0, 0, 0);
    }

    const int z = n0 >> 10;  // block-uniform
    const float* bias = (MODE == 1) ? b0 : ((z == 0) ? b0 : (z == 1) ? b1 : b2);
#pragma unroll
    for (int m = 0; m < 4; ++m)
#pragma unroll
        for (int n = 0; n < 4; ++n)
#pragma unroll
            for (int r = 0; r < 4; ++r) {
                int grow = m0 + wr + m * 16 + (lane >> 4) * 4 + r;
                int gcol = n0 + wc + n * 16 + (lane & 15);
                if (MODE == 0) {
                    int colN = gcol & 1023;
                    float val = acc[m][n][r] + bias[colN];
                    int b_ = grow >> 11, s_ = grow & 2047;
                    int h = colN >> 6, hd = colN & 63;
                    if (z == 2) {
                        // V^T[bh][hd][t]
                        ((bf16*)outp)[(size_t)z * 4194304 +
                                      ((size_t)(b_ * N_HEADS + h) * HEAD_DIM + hd) * SEQ + s_] =
                            (bf16)val;
                    } else {
                        ((bf16*)outp)[(size_t)z * 4194304 +
                                      ((size_t)(b_ * N_HEADS + h) * SEQ + s_) * HEAD_DIM + hd] =
                            (bf16)val;
                    }
                } else {
                    float val = acc[m][n][r] + bias[gcol];
                    ((float*)outp)[(size_t)grow * D_MODEL + gcol] = val;
                }
            }
}

// ---------------- flash-style causal attention, barrier-free ----------------
// grid 256 blocks x 512 threads (8 independent waves). Each wave owns one
// 32-row q-block of one (b,h). K and V^T B-fragments are loaded DIRECTLY from
// global (L2-resident, 512KB/bh) -- no K/V LDS, no __syncthreads. Only a
// wave-private P buffer round-trips through LDS.
// Balance: SIMD k of every block gets the task pair {j, 63-j} -> every SIMD
// executes 32-33 KV-tile iterations; zero tail.
__global__ __launch_bounds__(512) void attn_k(const bf16* __restrict__ Qg,
                                              const bf16* __restrict__ Kg,
                                              const bf16* __restrict__ VTg,
                                              bf16* __restrict__ AO) {
    __shared__ alignas(16) bf16 Ps[8][2][16 * 64];
    const int tid = threadIdx.x, wid = tid >> 6, lane = tid & 63;
    const int m = lane & 15, h = lane >> 4;
    const int s3 = blockIdx.x >> 5;   // 0..7
    const int bh = blockIdx.x & 31;
    // wid 0..3 -> heavy j = 63 - (wid*8+s3); wid 4..7 -> light j = (wid-4)*8+s3
    const int j = (wid < 4) ? (63 - (wid * 8 + s3)) : ((wid - 4) * 8 + s3);
    const int q0 = j * 32;
    const size_t base = (size_t)bh * SEQ * HEAD_DIM;
    const bf16* VT = VTg + (size_t)bh * HEAD_DIM * SEQ;

    // Q A-fragments: lane holds Q[q0+sub*16+m][kc*32 + h*8 + jj]
    bf16x8 aq[2][2];
#pragma unroll
    for (int sub = 0; sub < 2; ++sub)
#pragma unroll
        for (int kc = 0; kc < 2; ++kc)
            aq[sub][kc] = *(const bf16x8*)
                &Qg[base + (size_t)(q0 + sub * 16 + m) * HEAD_DIM + kc * 32 + h * 8];

    f32x4 o[2][4] = {};
    float mrow[2][4], lrow[2][4];
#pragma unroll
    for (int sub = 0; sub < 2; ++sub)
#pragma unroll
        for (int r = 0; r < 4; ++r) { mrow[sub][r] = -__builtin_inff(); lrow[sub][r] = 0.f; }

    const int nt = (j >> 1) + 1;
    for (int it = 0; it < nt; ++it) {
        const int t0 = it * 64;

        // K B-fragments direct from global: K[t0+tf*16+m][kc*32+h*8 ..+8]
        bf16x8 kf[4][2];
#pragma unroll
        for (int tf = 0; tf < 4; ++tf)
#pragma unroll
            for (int kc = 0; kc < 2; ++kc)
                kf[tf][kc] = *(const bf16x8*)
                    &Kg[base + (size_t)(t0 + tf * 16 + m) * HEAD_DIM + kc * 32 + h * 8];

        // ---- QK^T ----
        f32x4 s[2][4];
        __builtin_amdgcn_s_setprio(1);
#pragma unroll
        for (int sub = 0; sub < 2; ++sub)
#pragma unroll
            for (int tf = 0; tf < 4; ++tf) {
                f32x4 z = {};
                z = __builtin_amdgcn_mfma_f32_16x16x32_bf16(aq[sub][0], kf[tf][0], z, 0, 0, 0);
                z = __builtin_amdgcn_mfma_f32_16x16x32_bf16(aq[sub][1], kf[tf][1], z, 0, 0, 0);
                s[sub][tf] = z;
            }
        __builtin_amdgcn_s_setprio(0);

        // V^T B-fragments (independent; latency hides under softmax)
        bf16x8 vf[4][2];
#pragma unroll
        for (int nf = 0; nf < 4; ++nf)
#pragma unroll
            for (int kc = 0; kc < 2; ++kc)
                vf[nf][kc] = *(const bf16x8*)
                    &VT[(size_t)(nf * 16 + m) * SEQ + t0 + kc * 32 + h * 8];

        // scale; causal mask only on the last tile
#pragma unroll
        for (int sub = 0; sub < 2; ++sub)
#pragma unroll
            for (int tf = 0; tf < 4; ++tf)
#pragma unroll
                for (int r = 0; r < 4; ++r) s[sub][tf][r] *= 0.125f;
        if (it == nt - 1) {
#pragma unroll
            for (int sub = 0; sub < 2; ++sub)
#pragma unroll
                for (int tf = 0; tf < 4; ++tf)
#pragma unroll
                    for (int r = 0; r < 4; ++r) {
                        int gq = q0 + sub * 16 + h * 4 + r;
                        int gt = t0 + tf * 16 + m;
                        if (gt > gq) s[sub][tf][r] = -__builtin_inff();
                    }
        }

        // ---- online softmax (row-reduce across the 16 lanes of each h-group) ----
#pragma unroll
        for (int sub = 0; sub < 2; ++sub) {
            float mx[4];
#pragma unroll
            for (int r = 0; r < 4; ++r)
                mx[r] = fmaxf(fmaxf(s[sub][0][r], s[sub][1][r]),
                              fmaxf(s[sub][2][r], s[sub][3][r]));
#pragma unroll
            for (int off = 1; off < 16; off <<= 1)
#pragma unroll
                for (int r = 0; r < 4; ++r) mx[r] = fmaxf(mx[r], __shfl_xor(mx[r], off));
            float sf[4];
#pragma unroll
            for (int r = 0; r < 4; ++r) {
                float mn = fmaxf(mrow[sub][r], mx[r]);
                sf[r] = __expf(mrow[sub][r] - mn);
                mrow[sub][r] = mn;
            }
            float rs[4] = {0.f, 0.f, 0.f, 0.f};
#pragma unroll
            for (int tf = 0; tf < 4; ++tf)
#pragma unroll
                for (int r = 0; r < 4; ++r) {
                    float p = __expf(s[sub][tf][r] - mrow[sub][r]);
                    s[sub][tf][r] = p;
                    rs[r] += p;
                }
#pragma unroll
            for (int off = 1; off < 16; off <<= 1)
#pragma unroll
                for (int r = 0; r < 4; ++r) rs[r] += __shfl_xor(rs[r], off);
#pragma unroll
            for (int r = 0; r < 4; ++r) lrow[sub][r] = lrow[sub][r] * sf[r] + rs[r];
#pragma unroll
            for (int nf = 0; nf < 4; ++nf)
#pragma unroll
                for (int r = 0; r < 4; ++r) o[sub][nf][r] *= sf[r];

            // P -> wave-private LDS (swizzled; write 2 lanes/dword-merge, read balanced)
            char* Psb = (char*)&Ps[wid][sub][0];
#pragma unroll
            for (int tf = 0; tf < 4; ++tf)
#pragma unroll
                for (int r = 0; r < 4; ++r) {
                    int i = h * 4 + r;
                    int t = tf * 16 + m;
                    *(bf16*)(Psb + i * 128 + ((2 * t) ^ (h << 5))) = (bf16)s[sub][tf][r];
                }
        }

        // ---- PV ----
        __builtin_amdgcn_s_setprio(1);
#pragma unroll
        for (int sub = 0; sub < 2; ++sub) {
            char* Psb = (char*)&Ps[wid][sub][0];
#pragma unroll
            for (int kc = 0; kc < 2; ++kc) {
                bf16x8 ap = *(bf16x8*)(Psb + m * 128 +
                                       ((2 * (kc * 32 + h * 8)) ^ ((m >> 2) << 5)));
#pragma unroll
                for (int nf = 0; nf < 4; ++nf)
                    o[sub][nf] = __builtin_amdgcn_mfma_f32_16x16x32_bf16(
                        ap, vf[nf][kc], o[sub][nf], 0, 0, 0);
            }
        }
        __builtin_amdgcn_s_setprio(0);
    }

    const int b_ = bh >> 4, hh = bh & 15;
#pragma unroll
    for (int sub = 0; sub < 2; ++sub)
#pragma unroll
        for (int nf = 0; nf < 4; ++nf)
#pragma unroll
            for (int r = 0; r < 4; ++r) {
                int s_ = q0 + sub * 16 + h * 4 + r;
                float val = o[sub][nf][r] / lrow[sub][r];
                AO[((size_t)(b_ * SEQ + s_)) * D_MODEL + hh * HEAD_DIM + nf * 16 + m] =
                    (bf16)val;
            }
}

extern "C" void kernel_launch(void* const* d_in, const int* in_sizes, int n_in,
                              void* d_out, int out_size, void* d_ws, size_t ws_size,
                              hipStream_t stream) {
    const float* x  = (const float*)d_in[0];
    const float* Wq = (const float*)d_in[1];
    const float* bq = (const float*)d_in[2];
    const float* Wk = (const float*)d_in[3];
    const float* bk = (const float*)d_in[4];
    const float* Wv = (const float*)d_in[5];
    const float* bv = (const float*)d_in[6];
    const float* Wo = (const float*)d_in[7];
    const float* bo = (const float*)d_in[8];

    char* ws = (char*)d_ws;
    const size_t MB = 1u << 20;
    bf16* wt = (bf16*)ws;                  // 4 x [1024][1024] bf16 (QKV contiguous)
    bf16* xb = (bf16*)(ws + 8 * MB);       // [4096][1024] bf16
    bf16* Qb = (bf16*)(ws + 16 * MB);      // Q [32][2048][64]; K follows; then V^T [32][64][2048]
    bf16* AO = (bf16*)(ws + 40 * MB);      // [4096][1024] bf16

    const size_t WSTRIDE = (size_t)D_MODEL * D_MODEL;

    cvt_x<<<dim3(MROWS * D_MODEL / 4 / 256), dim3(256), 0, stream>>>(x, xb);
    cvt_wt<<<dim3(32, 32, 4), dim3(32, 32), 0, stream>>>(Wq, Wk, Wv, Wo, wt);

    // fused QKV projection: N = 3072 over contiguous [3072][1024] weight
    gemm_k<0><<<dim3(24, 32), dim3(256), 0, stream>>>(xb, wt, bq, bk, bv, Qb);

    bf16* Kb = Qb + 4194304;
    bf16* VTb = Qb + 2 * 4194304;
    attn_k<<<dim3(256), dim3(512), 0, stream>>>(Qb, Kb, VTb, AO);

    gemm_k<1><<<dim3(8, 32), dim3(256), 0, stream>>>(AO, wt + 3 * WSTRIDE, bo, bo, bo, d_out);
}